// Round 2
// baseline (435.062 us; speedup 1.0000x reference)
//
#include <hip/hip_runtime.h>

#define N_NODES 100000
#define D_FEAT 128
#define N_CLASSES 32
#define BSHIFT 8
#define NB 391            // ceil(100000/256) dst buckets of 256 nodes
#define EPB 4096          // edges per partition block
#define CAPB 4608         // per-bucket region capacity (mean 4092 + 8 sigma)

typedef __attribute__((ext_vector_type(8))) short short8;
typedef __attribute__((ext_vector_type(4))) float f32x4;

__device__ __forceinline__ unsigned short f2bf(float f) {
  unsigned u = __float_as_uint(f);
  u += 0x7fffu + ((u >> 16) & 1);   // round-to-nearest-even
  return (unsigned short)(u >> 16);
}

// ---------- prep: W -> bf16 + zero bucket counters (one tiny dispatch) ----------
__global__ __launch_bounds__(256) void gin_prep(const float* __restrict__ W,
                                                unsigned short* __restrict__ Wb,
                                                int* __restrict__ gcount) {
  int i = blockIdx.x * 256 + threadIdx.x;
  if (i < D_FEAT * N_CLASSES) Wb[i] = f2bf(W[i]);
  if (i < NB) gcount[i] = 0;
}

// ---------- fused mid kernel: blocks [0,GBr) partition edges, rest do MFMA proj ----------
// Partition: dst kept in registers (single global read). Per-block LDS histogram ->
// reserve per-bucket global ranges via ONE atomicAdd(gcount[b], cnt[b]) each ->
// local counting-scatter into sorted[] -> flush with binary-search-derived global
// address (no gaddr[] staging: LDS 39.3 -> 23.1 KB, 4 -> 6 blocks/CU).
// Projection: wave = 16 nodes x 32 classes, verified B^T fragment pattern.
__global__ __launch_bounds__(256) void gin_mid(
    const float* __restrict__ x, const unsigned short* __restrict__ Wb,
    float* __restrict__ y,
    const int* __restrict__ src, const int* __restrict__ dst,
    int* __restrict__ gcount, unsigned* __restrict__ bucketed,
    int E, int GBr) {
  __shared__ int cnt[NB];
  __shared__ int cur[NB];
  __shared__ int loff[NB + 1];
  __shared__ int gbase[NB];
  __shared__ int part[256];
  __shared__ unsigned sorted[EPB];   // 16 KB
  int tid = threadIdx.x;

  if ((int)blockIdx.x >= GBr) {
    // ================= projection path =================
    int pb = blockIdx.x - GBr;
    int wave = tid >> 6, lane = tid & 63;
    int node_base = pb * 64 + wave * 16;
    if (node_base >= N_NODES) return;
    int m = lane & 15, quad = lane >> 4;

    short8 bfrag[2][4];
#pragma unroll
    for (int cb = 0; cb < 2; ++cb) {
      const unsigned short* wr = Wb + (cb * 16 + m) * D_FEAT + quad * 8;
#pragma unroll
      for (int ks = 0; ks < 4; ++ks)
        bfrag[cb][ks] = *(const short8*)(wr + ks * 32);
    }

    const float* xr = x + (size_t)(node_base + m) * D_FEAT + quad * 8;
    short8 afrag[4];
#pragma unroll
    for (int ks = 0; ks < 4; ++ks) {
      float4 f0 = *(const float4*)(xr + ks * 32);
      float4 f1 = *(const float4*)(xr + ks * 32 + 4);
      float fl[8] = {f0.x, f0.y, f0.z, f0.w, f1.x, f1.y, f1.z, f1.w};
      short8 a;
#pragma unroll
      for (int j = 0; j < 8; ++j) a[j] = (short)f2bf(fl[j]);
      afrag[ks] = a;
    }

    f32x4 acc0 = {0.f, 0.f, 0.f, 0.f};
    f32x4 acc1 = {0.f, 0.f, 0.f, 0.f};
#pragma unroll
    for (int ks = 0; ks < 4; ++ks) {
      acc0 = __builtin_amdgcn_mfma_f32_16x16x32_bf16(afrag[ks], bfrag[0][ks], acc0, 0, 0, 0);
      acc1 = __builtin_amdgcn_mfma_f32_16x16x32_bf16(afrag[ks], bfrag[1][ks], acc1, 0, 0, 0);
    }

#pragma unroll
    for (int r = 0; r < 4; ++r) {
      int node = node_base + quad * 4 + r;
      y[(size_t)node * N_CLASSES + m] = acc0[r];
      y[(size_t)node * N_CLASSES + 16 + m] = acc1[r];
    }
    return;
  }

  // ================= partition path =================
  int blk = blockIdx.x;
  for (int i = tid; i < NB; i += 256) {
    cnt[i] = 0;
    cur[i] = 0;
  }
  __syncthreads();
  int base = blk * EPB;
  bool full = (base + EPB <= E);

  // single global read of dst, held in registers
  int dv[16];
  unsigned sv[16];
  if (full) {
#pragma unroll
    for (int k = 0; k < 16; ++k) dv[k] = dst[base + k * 256 + tid];
#pragma unroll
    for (int k = 0; k < 16; ++k) sv[k] = (unsigned)src[base + k * 256 + tid];
  } else {
#pragma unroll
    for (int k = 0; k < 16; ++k) {
      int e = base + k * 256 + tid;
      dv[k] = (e < E) ? dst[e] : -1;
      sv[k] = (e < E) ? (unsigned)src[e] : 0u;
    }
  }
#pragma unroll
  for (int k = 0; k < 16; ++k)
    if (dv[k] >= 0) atomicAdd(&cnt[dv[k] >> BSHIFT], 1);
  __syncthreads();

  // reserve global ranges (order within bucket doesn't matter)
  for (int i = tid; i < NB; i += 256) {
    int c = cnt[i];
    gbase[i] = c ? atomicAdd(&gcount[i], c) : 0;
  }
  // local exclusive scan of cnt -> loff
  int i0 = tid * 2;
  int v0 = (i0 < NB) ? cnt[i0] : 0;
  int v1 = (i0 + 1 < NB) ? cnt[i0 + 1] : 0;
  int s0 = v0 + v1;
  part[tid] = s0;
  __syncthreads();
  for (int o = 1; o < 256; o <<= 1) {
    int t = (tid >= o) ? part[tid - o] : 0;
    __syncthreads();
    part[tid] += t;
    __syncthreads();
  }
  int run = part[tid] - s0;
  if (i0 < NB) loff[i0] = run;
  if (i0 + 1 < NB) loff[i0 + 1] = run + v0;
  if (tid == 255) loff[NB] = part[255];
  __syncthreads();

  // counting-scatter into LDS (grouped by bucket)
#pragma unroll
  for (int k = 0; k < 16; ++k) {
    if (dv[k] >= 0) {
      int b = dv[k] >> BSHIFT;
      int r = atomicAdd(&cur[b], 1);
      sorted[loff[b] + r] = sv[k] | ((unsigned)(dv[k] & 255) << 17);
    }
  }
  __syncthreads();

  // flush: global addr = gbase[b] + (i - loff[b]), b via binary search in loff
  int ltot = loff[NB];
  for (int i = tid; i < ltot; i += 256) {
    int lo = 0, hi = NB;
    while (hi - lo > 1) {
      int md = (lo + hi) >> 1;
      if (loff[md] <= i) lo = md; else hi = md;
    }
    int ga = gbase[lo] + (i - loff[lo]);
    if (ga < CAPB) bucketed[(size_t)lo * CAPB + ga] = sorted[i];
  }
}

// ---------- gather: order-free LDS accumulation, 4 blocks per bucket ----------
// Each 32-lane group owns one edge per iteration: broadcast-read the packed entry,
// coalesced-read the full 128 B y row (y[src*32+lane]), ds_add_f32 into the
// 64x32 accumulator (bank = lane: 2-way wave64 aliasing = free). No counting
// sort, no second pass, no shuffle reduce.
__global__ __launch_bounds__(512) void gin_gather_acc(
    const int* __restrict__ gcount, const unsigned* __restrict__ bucketed,
    const float* __restrict__ y, const float* __restrict__ bias,
    float* __restrict__ out) {
  __shared__ float acc[64 * 32];   // 8 KB
  int tid = threadIdx.x;
  int bk = blockIdx.x >> 2;
  int qq = blockIdx.x & 3;
  int len = gcount[bk];
  if (len > CAPB) len = CAPB;
  const unsigned* bb = bucketed + (size_t)bk * CAPB;
  for (int i = tid; i < 64 * 32; i += 512) acc[i] = 0.f;
  __syncthreads();
  int grp = tid >> 5, lane = tid & 31;
#pragma unroll 2
  for (int i = grp; i < len; i += 16) {
    unsigned p = bb[i];                      // 32-lane broadcast read
    int n8 = (int)((p >> 17) & 255u);
    if ((n8 >> 6) == qq) {                   // group-uniform branch
      float v = y[(size_t)(p & 0x1FFFF) * 32 + lane];
      atomicAdd(&acc[(n8 & 63) * 32 + lane], v);
    }
  }
  __syncthreads();
  // epilogue: out = acc + y + b, coalesced float4 (exactly 1 per thread)
  int base_node = (bk << 8) + (qq << 6);
  const float4* y4 = (const float4*)y;
  const float4* b4 = (const float4*)bias;
  const float4* a4 = (const float4*)acc;
  int i = tid;                               // 64*8 == 512
  int node = base_node + (i >> 3);
  int q = i & 7;
  if (node < N_NODES) {
    float4 a = a4[i];
    float4 yv = y4[(size_t)node * 8 + q];
    float4 bq = b4[q];
    float4 r;
    r.x = a.x + yv.x + bq.x;
    r.y = a.y + yv.y + bq.y;
    r.z = a.z + yv.z + bq.z;
    r.w = a.w + yv.w + bq.w;
    ((float4*)out)[(size_t)node * 8 + q] = r;
  }
}

// ---------- fallback: bias init + atomic scatter ----------
__global__ __launch_bounds__(256) void gin_bias_init(
    const float* __restrict__ y, const float* __restrict__ b,
    float* __restrict__ out) {
  int gid = blockIdx.x * 256 + threadIdx.x;
  if (gid < N_NODES * N_CLASSES) out[gid] = y[gid] + b[gid & 31];
}
__global__ __launch_bounds__(256) void gin_scatter_fb(
    const int* __restrict__ src, const int* __restrict__ dst,
    const float* __restrict__ y, float* __restrict__ out, int n_edges) {
  long long gid = (long long)blockIdx.x * 256 + threadIdx.x;
  int e = (int)(gid >> 5);
  int c = (int)(gid & 31);
  if (e >= n_edges) return;
  atomicAdd(&out[(size_t)dst[e] * N_CLASSES + c],
            y[(size_t)src[e] * N_CLASSES + c]);
}

extern "C" void kernel_launch(void* const* d_in, const int* in_sizes, int n_in,
                              void* d_out, int out_size, void* d_ws, size_t ws_size,
                              hipStream_t stream) {
  const float* x = (const float*)d_in[0];
  const int* edge_index = (const int*)d_in[1];
  const float* W = (const float*)d_in[2];
  const float* b = (const float*)d_in[3];
  float* out = (float*)d_out;

  int E = in_sizes[1] / 2;
  const int* src = edge_index;
  const int* dst = edge_index + E;

  int GBr = (E + EPB - 1) / EPB;      // 391 for E=1.6M
  int pblocks = (N_NODES + 63) / 64;  // 1563 projection blocks (4 waves x 16 nodes)

  char* ws = (char*)d_ws;
  size_t sz_y = (size_t)N_NODES * N_CLASSES * 4;              // 12.8 MB
  size_t sz_wb = (D_FEAT * N_CLASSES * 2 + 15) & ~15ull;      // 8 KB bf16 W
  size_t sz_bucketed = (((size_t)NB * CAPB * 4) + 15) & ~15ull;  // 7.2 MB
  size_t sz_gcnt = ((size_t)NB * 4 + 15) & ~15ull;

  float* y = (float*)ws;
  unsigned short* Wb = (unsigned short*)(ws + sz_y);
  unsigned* bucketed = (unsigned*)(ws + sz_y + sz_wb);
  int* gcount = (int*)(ws + sz_y + sz_wb + sz_bucketed);
  size_t need = sz_y + sz_wb + sz_bucketed + sz_gcnt;

  if (ws_size < need) {
    // fallback: project (all blocks take proj path with GBr=0) + atomic scatter
    gin_prep<<<16, 256, 0, stream>>>(W, Wb, (int*)ws);  // gcount scratch inside y; y fully overwritten next
    gin_mid<<<pblocks, 256, 0, stream>>>(x, Wb, y, src, dst, (int*)ws, (unsigned*)ws, E, 0);
    gin_bias_init<<<(N_NODES * N_CLASSES + 255) / 256, 256, 0, stream>>>(y, b, out);
    long long t2 = (long long)E * N_CLASSES;
    gin_scatter_fb<<<(int)((t2 + 255) / 256), 256, 0, stream>>>(src, dst, y, out, E);
    return;
  }

  gin_prep<<<16, 256, 0, stream>>>(W, Wb, gcount);
  gin_mid<<<GBr + pblocks, 256, 0, stream>>>(x, Wb, y, src, dst, gcount, bucketed, E, GBr);
  gin_gather_acc<<<NB * 4, 512, 0, stream>>>(gcount, bucketed, y, b, out);
}

// Round 3
// 208.443 us; speedup vs baseline: 2.0872x; 2.0872x over previous
//
#include <hip/hip_runtime.h>

#define N_NODES 100000
#define D_FEAT 128
#define N_CLASSES 32
#define EPB 4096          // edges per scatter block
#define CAPN 64           // per-node neighbor capacity (mean deg 16, Poisson tail ~1e-17)

typedef __attribute__((ext_vector_type(8))) short short8;
typedef __attribute__((ext_vector_type(4))) float f32x4;

__device__ __forceinline__ unsigned short f2bf(float f) {
  unsigned u = __float_as_uint(f);
  u += 0x7fffu + ((u >> 16) & 1);   // round-to-nearest-even
  return (unsigned short)(u >> 16);
}

// ---------- prep: W -> bf16 + zero per-node degree counters ----------
__global__ __launch_bounds__(256) void gin_prep(const float* __restrict__ W,
                                                unsigned short* __restrict__ Wb,
                                                int* __restrict__ deg) {
  int i = blockIdx.x * 256 + threadIdx.x;
  if (i < D_FEAT * N_CLASSES) Wb[i] = f2bf(W[i]);
  if (i < N_NODES) deg[i] = 0;
}

// ---------- fused mid: blocks [0,GBr) scatter edges to per-node lists, rest MFMA proj ----------
// Scatter: one native int atomicAdd per edge (distributed over 100K counters) +
// one 4B scattered write. No LDS at all -> projection blocks not LDS-capped.
// Projection: wave = 16 nodes x 32 classes, verified B^T fragment pattern.
__global__ __launch_bounds__(256) void gin_mid(
    const float* __restrict__ x, const unsigned short* __restrict__ Wb,
    float* __restrict__ y,
    const int* __restrict__ src, const int* __restrict__ dst,
    int* __restrict__ deg, unsigned* __restrict__ node_list,
    int E, int GBr) {
  int tid = threadIdx.x;

  if ((int)blockIdx.x >= GBr) {
    // ================= projection path =================
    int pb = blockIdx.x - GBr;
    int wave = tid >> 6, lane = tid & 63;
    int node_base = pb * 64 + wave * 16;
    if (node_base >= N_NODES) return;
    int m = lane & 15, quad = lane >> 4;

    short8 bfrag[2][4];
#pragma unroll
    for (int cb = 0; cb < 2; ++cb) {
      const unsigned short* wr = Wb + (cb * 16 + m) * D_FEAT + quad * 8;
#pragma unroll
      for (int ks = 0; ks < 4; ++ks)
        bfrag[cb][ks] = *(const short8*)(wr + ks * 32);
    }

    const float* xr = x + (size_t)(node_base + m) * D_FEAT + quad * 8;
    short8 afrag[4];
#pragma unroll
    for (int ks = 0; ks < 4; ++ks) {
      float4 f0 = *(const float4*)(xr + ks * 32);
      float4 f1 = *(const float4*)(xr + ks * 32 + 4);
      float fl[8] = {f0.x, f0.y, f0.z, f0.w, f1.x, f1.y, f1.z, f1.w};
      short8 a;
#pragma unroll
      for (int j = 0; j < 8; ++j) a[j] = (short)f2bf(fl[j]);
      afrag[ks] = a;
    }

    f32x4 acc0 = {0.f, 0.f, 0.f, 0.f};
    f32x4 acc1 = {0.f, 0.f, 0.f, 0.f};
#pragma unroll
    for (int ks = 0; ks < 4; ++ks) {
      acc0 = __builtin_amdgcn_mfma_f32_16x16x32_bf16(afrag[ks], bfrag[0][ks], acc0, 0, 0, 0);
      acc1 = __builtin_amdgcn_mfma_f32_16x16x32_bf16(afrag[ks], bfrag[1][ks], acc1, 0, 0, 0);
    }

#pragma unroll
    for (int r = 0; r < 4; ++r) {
      int node = node_base + quad * 4 + r;
      y[(size_t)node * N_CLASSES + m] = acc0[r];
      y[(size_t)node * N_CLASSES + 16 + m] = acc1[r];
    }
    return;
  }

  // ================= scatter path (no LDS) =================
  int base = blockIdx.x * EPB;
  bool full = (base + EPB <= E);
  int dv[16];
  unsigned sv[16];
  if (full) {
#pragma unroll
    for (int k = 0; k < 16; ++k) dv[k] = dst[base + k * 256 + tid];
#pragma unroll
    for (int k = 0; k < 16; ++k) sv[k] = (unsigned)src[base + k * 256 + tid];
  } else {
#pragma unroll
    for (int k = 0; k < 16; ++k) {
      int e = base + k * 256 + tid;
      dv[k] = (e < E) ? dst[e] : -1;
      sv[k] = (e < E) ? (unsigned)src[e] : 0u;
    }
  }
#pragma unroll
  for (int k = 0; k < 16; ++k) {
    if (dv[k] >= 0) {
      int idx = atomicAdd(&deg[dv[k]], 1);
      if (idx < CAPN) node_list[(size_t)dv[k] * CAPN + idx] = sv[k];
    }
  }
}

// ---------- gather: pure register CSR accumulation, no LDS, no atomics ----------
// 8 threads per node (q = tid&7 owns one float4 column). Inner loop: 4 edges per
// iteration -> 4 independent y-row float4 loads in flight (the round-0 MLP
// pattern), src indices read as one uint4. Epilogue fused: out = acc + y + b.
__global__ __launch_bounds__(512) void gin_gather_nl(
    const int* __restrict__ deg, const unsigned* __restrict__ node_list,
    const float* __restrict__ y, const float* __restrict__ bias,
    float* __restrict__ out) {
  int tid = threadIdx.x;
  int node = blockIdx.x * 64 + (tid >> 3);
  int q = tid & 7;
  if (node >= N_NODES) return;
  int dg = deg[node];
  if (dg > CAPN) dg = CAPN;
  const unsigned* nl = node_list + (size_t)node * CAPN;
  const float4* y4 = (const float4*)y;
  float4 bq = ((const float4*)bias)[q];
  float4 self = y4[(size_t)node * 8 + q];
  float4 acc;
  acc.x = self.x + bq.x;
  acc.y = self.y + bq.y;
  acc.z = self.z + bq.z;
  acc.w = self.w + bq.w;
  int j = 0;
  for (; j + 4 <= dg; j += 4) {
    uint4 ss = *(const uint4*)(nl + j);    // 16B-aligned (node base 256B, j%4==0)
    float4 w0 = y4[(size_t)ss.x * 8 + q];
    float4 w1 = y4[(size_t)ss.y * 8 + q];
    float4 w2 = y4[(size_t)ss.z * 8 + q];
    float4 w3 = y4[(size_t)ss.w * 8 + q];
    acc.x += w0.x + w1.x + w2.x + w3.x;
    acc.y += w0.y + w1.y + w2.y + w3.y;
    acc.z += w0.z + w1.z + w2.z + w3.z;
    acc.w += w0.w + w1.w + w2.w + w3.w;
  }
  for (; j < dg; ++j) {
    float4 w = y4[(size_t)nl[j] * 8 + q];
    acc.x += w.x; acc.y += w.y; acc.z += w.z; acc.w += w.w;
  }
  ((float4*)out)[(size_t)node * 8 + q] = acc;
}

// ---------- fallback: bias init + atomic scatter ----------
__global__ __launch_bounds__(256) void gin_bias_init(
    const float* __restrict__ y, const float* __restrict__ b,
    float* __restrict__ out) {
  int gid = blockIdx.x * 256 + threadIdx.x;
  if (gid < N_NODES * N_CLASSES) out[gid] = y[gid] + b[gid & 31];
}
__global__ __launch_bounds__(256) void gin_scatter_fb(
    const int* __restrict__ src, const int* __restrict__ dst,
    const float* __restrict__ y, float* __restrict__ out, int n_edges) {
  long long gid = (long long)blockIdx.x * 256 + threadIdx.x;
  int e = (int)(gid >> 5);
  int c = (int)(gid & 31);
  if (e >= n_edges) return;
  atomicAdd(&out[(size_t)dst[e] * N_CLASSES + c],
            y[(size_t)src[e] * N_CLASSES + c]);
}

extern "C" void kernel_launch(void* const* d_in, const int* in_sizes, int n_in,
                              void* d_out, int out_size, void* d_ws, size_t ws_size,
                              hipStream_t stream) {
  const float* x = (const float*)d_in[0];
  const int* edge_index = (const int*)d_in[1];
  const float* W = (const float*)d_in[2];
  const float* b = (const float*)d_in[3];
  float* out = (float*)d_out;

  int E = in_sizes[1] / 2;
  const int* src = edge_index;
  const int* dst = edge_index + E;

  int GBr = (E + EPB - 1) / EPB;      // 391 for E=1.6M
  int pblocks = (N_NODES + 63) / 64;  // 1563 projection blocks (4 waves x 16 nodes)

  char* ws = (char*)d_ws;
  size_t sz_y = (size_t)N_NODES * N_CLASSES * 4;                 // 12.8 MB
  size_t sz_wb = (D_FEAT * N_CLASSES * 2 + 15) & ~15ull;         // 8 KB bf16 W
  size_t sz_nl = (((size_t)N_NODES * CAPN * 4) + 15) & ~15ull;   // 25.6 MB
  size_t sz_deg = ((size_t)N_NODES * 4 + 15) & ~15ull;           // 400 KB

  float* y = (float*)ws;
  unsigned short* Wb = (unsigned short*)(ws + sz_y);
  unsigned* node_list = (unsigned*)(ws + sz_y + sz_wb);
  int* deg = (int*)(ws + sz_y + sz_wb + sz_nl);
  size_t need = sz_y + sz_wb + sz_nl + sz_deg;

  // mean-degree guard: CAPN=64 is sized for E/N ~ 16 (Poisson). If the edge set
  // is much denser, overflow would silently drop edges -> use exact fallback.
  bool dense = (long long)E > (long long)N_NODES * 28;

  if (ws_size < need || dense) {
    gin_prep<<<16, 256, 0, stream>>>(W, Wb, (int*)ws);  // scratch; y overwritten next
    gin_mid<<<pblocks, 256, 0, stream>>>(x, Wb, y, src, dst, (int*)ws, (unsigned*)ws, E, 0);
    gin_bias_init<<<(N_NODES * N_CLASSES + 255) / 256, 256, 0, stream>>>(y, b, out);
    long long t2 = (long long)E * N_CLASSES;
    gin_scatter_fb<<<(int)((t2 + 255) / 256), 256, 0, stream>>>(src, dst, y, out, E);
    return;
  }

  gin_prep<<<(N_NODES + 255) / 256, 256, 0, stream>>>(W, Wb, deg);
  gin_mid<<<GBr + pblocks, 256, 0, stream>>>(x, Wb, y, src, dst, deg, node_list, E, GBr);
  gin_gather_nl<<<(N_NODES + 63) / 64, 512, 0, stream>>>(deg, node_list, y, b, out);
}

// Round 4
// 155.677 us; speedup vs baseline: 2.7947x; 1.3390x over previous
//
#include <hip/hip_runtime.h>

#define N_NODES 100000
#define D_FEAT 128
#define N_CLASSES 32
#define BSHIFT 8
#define NB 391            // ceil(100000/256) dst buckets of 256 nodes
#define EPB 4096          // edges per partition block
#define CAPB 5120         // per-bucket region capacity (mean 4092 + >8 sigma)
#define GCAP 1536         // per-quarter sorted capacity (mean 1023 + >8 sigma)

typedef __attribute__((ext_vector_type(8))) short short8;
typedef __attribute__((ext_vector_type(4))) float f32x4;

__device__ __forceinline__ unsigned short f2bf(float f) {
  unsigned u = __float_as_uint(f);
  u += 0x7fffu + ((u >> 16) & 1);   // round-to-nearest-even
  return (unsigned short)(u >> 16);
}

// ---------- prep: W -> bf16 + zero bucket counters ----------
__global__ __launch_bounds__(256) void gin_prep(const float* __restrict__ W,
                                                unsigned short* __restrict__ Wb,
                                                int* __restrict__ gcount) {
  int i = blockIdx.x * 256 + threadIdx.x;
  if (i < D_FEAT * N_CLASSES) Wb[i] = f2bf(W[i]);
  if (i < NB) gcount[i] = 0;
}

// ---------- fused mid: blocks [0,GBr) partition edges, rest MFMA projection ----------
// Partition: edges read ONCE into registers -> LDS histogram -> reserve global
// per-bucket ranges (one atomicAdd per (block,bucket); within-bucket order is
// irrelevant so no global scan) -> LDS counting-scatter groups edges by bucket ->
// flush in runs of ~10 contiguous words per bucket (write amp ~2x, vs 16x for
// direct per-node scatter, round-3 lesson). Flush address recovered by binary
// search over loff (no gaddr staging: LDS 39.3 -> 22.4 KB -> 6 blocks/CU).
__global__ __launch_bounds__(256) void gin_mid(
    const float* __restrict__ x, const unsigned short* __restrict__ Wb,
    float* __restrict__ y,
    const int* __restrict__ src, const int* __restrict__ dst,
    int* __restrict__ gcount, unsigned* __restrict__ bucketed,
    int E, int GBr) {
  __shared__ int cnt[NB];
  __shared__ int cur[NB];
  __shared__ int loff[NB + 1];
  __shared__ int gbase[NB];
  __shared__ int part[256];
  __shared__ unsigned sorted[EPB];   // 16 KB
  int tid = threadIdx.x;

  if ((int)blockIdx.x >= GBr) {
    // ================= projection path =================
    int pb = blockIdx.x - GBr;
    int wave = tid >> 6, lane = tid & 63;
    int node_base = pb * 64 + wave * 16;
    if (node_base >= N_NODES) return;
    int m = lane & 15, quad = lane >> 4;

    short8 bfrag[2][4];
#pragma unroll
    for (int cb = 0; cb < 2; ++cb) {
      const unsigned short* wr = Wb + (cb * 16 + m) * D_FEAT + quad * 8;
#pragma unroll
      for (int ks = 0; ks < 4; ++ks)
        bfrag[cb][ks] = *(const short8*)(wr + ks * 32);
    }

    const float* xr = x + (size_t)(node_base + m) * D_FEAT + quad * 8;
    short8 afrag[4];
#pragma unroll
    for (int ks = 0; ks < 4; ++ks) {
      float4 f0 = *(const float4*)(xr + ks * 32);
      float4 f1 = *(const float4*)(xr + ks * 32 + 4);
      float fl[8] = {f0.x, f0.y, f0.z, f0.w, f1.x, f1.y, f1.z, f1.w};
      short8 a;
#pragma unroll
      for (int j = 0; j < 8; ++j) a[j] = (short)f2bf(fl[j]);
      afrag[ks] = a;
    }

    f32x4 acc0 = {0.f, 0.f, 0.f, 0.f};
    f32x4 acc1 = {0.f, 0.f, 0.f, 0.f};
#pragma unroll
    for (int ks = 0; ks < 4; ++ks) {
      acc0 = __builtin_amdgcn_mfma_f32_16x16x32_bf16(afrag[ks], bfrag[0][ks], acc0, 0, 0, 0);
      acc1 = __builtin_amdgcn_mfma_f32_16x16x32_bf16(afrag[ks], bfrag[1][ks], acc1, 0, 0, 0);
    }

#pragma unroll
    for (int r = 0; r < 4; ++r) {
      int node = node_base + quad * 4 + r;
      y[(size_t)node * N_CLASSES + m] = acc0[r];
      y[(size_t)node * N_CLASSES + 16 + m] = acc1[r];
    }
    return;
  }

  // ================= partition path =================
  int blk = blockIdx.x;
  for (int i = tid; i < NB; i += 256) {
    cnt[i] = 0;
    cur[i] = 0;
  }
  __syncthreads();
  int base = blk * EPB;
  bool full = (base + EPB <= E);

  // single global read of the edge list, held in registers
  int dv[16];
  unsigned sv[16];
  if (full) {
#pragma unroll
    for (int k = 0; k < 16; ++k) dv[k] = dst[base + k * 256 + tid];
#pragma unroll
    for (int k = 0; k < 16; ++k) sv[k] = (unsigned)src[base + k * 256 + tid];
  } else {
#pragma unroll
    for (int k = 0; k < 16; ++k) {
      int e = base + k * 256 + tid;
      dv[k] = (e < E) ? dst[e] : -1;
      sv[k] = (e < E) ? (unsigned)src[e] : 0u;
    }
  }
#pragma unroll
  for (int k = 0; k < 16; ++k)
    if (dv[k] >= 0) atomicAdd(&cnt[dv[k] >> BSHIFT], 1);
  __syncthreads();

  // reserve global ranges
  for (int i = tid; i < NB; i += 256) {
    int c = cnt[i];
    gbase[i] = c ? atomicAdd(&gcount[i], c) : 0;
  }
  // local exclusive scan of cnt -> loff
  int i0 = tid * 2;
  int v0 = (i0 < NB) ? cnt[i0] : 0;
  int v1 = (i0 + 1 < NB) ? cnt[i0 + 1] : 0;
  int s0 = v0 + v1;
  part[tid] = s0;
  __syncthreads();
  for (int o = 1; o < 256; o <<= 1) {
    int t = (tid >= o) ? part[tid - o] : 0;
    __syncthreads();
    part[tid] += t;
    __syncthreads();
  }
  int run = part[tid] - s0;
  if (i0 < NB) loff[i0] = run;
  if (i0 + 1 < NB) loff[i0 + 1] = run + v0;
  if (tid == 255) loff[NB] = part[255];
  __syncthreads();

  // counting-scatter into LDS (grouped by bucket)
#pragma unroll
  for (int k = 0; k < 16; ++k) {
    if (dv[k] >= 0) {
      int b = dv[k] >> BSHIFT;
      int r = atomicAdd(&cur[b], 1);
      sorted[loff[b] + r] = sv[k] | ((unsigned)(dv[k] & 255) << 17);
    }
  }
  __syncthreads();

  // flush: global addr = gbase[b] + (i - loff[b]), b via binary search in loff
  int ltot = loff[NB];
  for (int i = tid; i < ltot; i += 256) {
    int lo = 0, hi = NB;
    while (hi - lo > 1) {
      int md = (lo + hi) >> 1;
      if (loff[md] <= i) lo = md; else hi = md;
    }
    int ga = gbase[lo] + (i - loff[lo]);
    if (ga < CAPB) bucketed[(size_t)lo * CAPB + ga] = sorted[i];
  }
}

// ---------- gather: 4 blocks/bucket; counting-sort quarter into LDS, then ----------
// 8-threads-per-node register accumulation (round-3 pattern, reading src indices
// from the sorted LDS segment). No slot splitting, no shuffle reduce.
__global__ __launch_bounds__(512) void gin_gather_s(
    const int* __restrict__ gcount, const unsigned* __restrict__ bucketed,
    const float* __restrict__ y, const float* __restrict__ bias,
    float* __restrict__ out) {
  __shared__ unsigned sorted[GCAP];  // 6 KB
  __shared__ int cnt[64];
  __shared__ int off[65];
  __shared__ int cur[64];
  int tid = threadIdx.x;
  int bk = blockIdx.x >> 2;
  int qq = blockIdx.x & 3;
  int len = gcount[bk];
  if (len > CAPB) len = CAPB;
  const unsigned* bb = bucketed + (size_t)bk * CAPB;
  if (tid < 64) cnt[tid] = 0;
  __syncthreads();
  for (int i = tid; i < len; i += 512) {
    unsigned p = bb[i];
    int n8 = (int)((p >> 17) & 255u);
    if ((n8 >> 6) == qq) atomicAdd(&cnt[n8 & 63], 1);
  }
  __syncthreads();
  if (tid == 0) off[0] = 0;
  if (tid < 64) off[tid + 1] = cnt[tid];
  __syncthreads();
  for (int o = 1; o < 64; o <<= 1) {
    int v = (tid < 64 && tid >= o) ? off[tid + 1 - o] : 0;
    __syncthreads();
    if (tid < 64) off[tid + 1] += v;
    __syncthreads();
  }
  if (tid < 64) cur[tid] = off[tid];
  __syncthreads();
  for (int i = tid; i < len; i += 512) {
    unsigned p = bb[i];
    int n8 = (int)((p >> 17) & 255u);
    if ((n8 >> 6) == qq) {
      int pos = atomicAdd(&cur[n8 & 63], 1);
      if (pos < GCAP) sorted[pos] = p;
    }
  }
  __syncthreads();
  // accumulate: 8 threads per node, q = tid&7 owns one float4 column
  int nl = tid >> 3;                 // node-in-quarter 0..63
  int q = tid & 7;
  int es = off[nl], ee = off[nl + 1];
  if (ee > GCAP) ee = GCAP;
  if (es > ee) es = ee;
  int node = (bk << 8) + (qq << 6) + nl;
  if (node >= N_NODES) return;
  const float4* y4 = (const float4*)y;
  float4 bq = ((const float4*)bias)[q];
  float4 self = y4[(size_t)node * 8 + q];
  float4 acc;
  acc.x = self.x + bq.x;
  acc.y = self.y + bq.y;
  acc.z = self.z + bq.z;
  acc.w = self.w + bq.w;
  int j = es;
  for (; j + 4 <= ee; j += 4) {
    unsigned s0 = sorted[j] & 0x1FFFF, s1 = sorted[j + 1] & 0x1FFFF;
    unsigned s2 = sorted[j + 2] & 0x1FFFF, s3 = sorted[j + 3] & 0x1FFFF;
    float4 w0 = y4[(size_t)s0 * 8 + q];
    float4 w1 = y4[(size_t)s1 * 8 + q];
    float4 w2 = y4[(size_t)s2 * 8 + q];
    float4 w3 = y4[(size_t)s3 * 8 + q];
    acc.x += w0.x + w1.x + w2.x + w3.x;
    acc.y += w0.y + w1.y + w2.y + w3.y;
    acc.z += w0.z + w1.z + w2.z + w3.z;
    acc.w += w0.w + w1.w + w2.w + w3.w;
  }
  for (; j < ee; ++j) {
    float4 w = y4[(size_t)(sorted[j] & 0x1FFFF) * 8 + q];
    acc.x += w.x; acc.y += w.y; acc.z += w.z; acc.w += w.w;
  }
  ((float4*)out)[(size_t)node * 8 + q] = acc;
}

// ---------- fallback: bias init + atomic scatter ----------
__global__ __launch_bounds__(256) void gin_bias_init(
    const float* __restrict__ y, const float* __restrict__ b,
    float* __restrict__ out) {
  int gid = blockIdx.x * 256 + threadIdx.x;
  if (gid < N_NODES * N_CLASSES) out[gid] = y[gid] + b[gid & 31];
}
__global__ __launch_bounds__(256) void gin_scatter_fb(
    const int* __restrict__ src, const int* __restrict__ dst,
    const float* __restrict__ y, float* __restrict__ out, int n_edges) {
  long long gid = (long long)blockIdx.x * 256 + threadIdx.x;
  int e = (int)(gid >> 5);
  int c = (int)(gid & 31);
  if (e >= n_edges) return;
  atomicAdd(&out[(size_t)dst[e] * N_CLASSES + c],
            y[(size_t)src[e] * N_CLASSES + c]);
}

extern "C" void kernel_launch(void* const* d_in, const int* in_sizes, int n_in,
                              void* d_out, int out_size, void* d_ws, size_t ws_size,
                              hipStream_t stream) {
  const float* x = (const float*)d_in[0];
  const int* edge_index = (const int*)d_in[1];
  const float* W = (const float*)d_in[2];
  const float* b = (const float*)d_in[3];
  float* out = (float*)d_out;

  int E = in_sizes[1] / 2;
  const int* src = edge_index;
  const int* dst = edge_index + E;

  int GBr = (E + EPB - 1) / EPB;      // 391 for E=1.6M
  int pblocks = (N_NODES + 63) / 64;  // 1563 projection blocks (4 waves x 16 nodes)

  char* ws = (char*)d_ws;
  size_t sz_y = (size_t)N_NODES * N_CLASSES * 4;                 // 12.8 MB
  size_t sz_wb = (D_FEAT * N_CLASSES * 2 + 15) & ~15ull;         // 8 KB bf16 W
  size_t sz_bucketed = (((size_t)NB * CAPB * 4) + 15) & ~15ull;  // 8.0 MB
  size_t sz_gcnt = ((size_t)NB * 4 + 15) & ~15ull;

  float* y = (float*)ws;
  unsigned short* Wb = (unsigned short*)(ws + sz_y);
  unsigned* bucketed = (unsigned*)(ws + sz_y + sz_wb);
  int* gcount = (int*)(ws + sz_y + sz_wb + sz_bucketed);
  size_t need = sz_y + sz_wb + sz_bucketed + sz_gcnt;

  // capacity guard: CAPB=5120 covers mean E/391 + 8 sigma up to E ~ 1.75M
  bool dense = E > 1750000;

  if (ws_size < need || dense) {
    gin_prep<<<16, 256, 0, stream>>>(W, Wb, (int*)ws);  // scratch; y overwritten next
    gin_mid<<<pblocks, 256, 0, stream>>>(x, Wb, y, src, dst, (int*)ws, (unsigned*)ws, E, 0);
    gin_bias_init<<<(N_NODES * N_CLASSES + 255) / 256, 256, 0, stream>>>(y, b, out);
    long long t2 = (long long)E * N_CLASSES;
    gin_scatter_fb<<<(int)((t2 + 255) / 256), 256, 0, stream>>>(src, dst, y, out, E);
    return;
  }

  gin_prep<<<16, 256, 0, stream>>>(W, Wb, gcount);
  gin_mid<<<GBr + pblocks, 256, 0, stream>>>(x, Wb, y, src, dst, gcount, bucketed, E, GBr);
  gin_gather_s<<<NB * 4, 512, 0, stream>>>(gcount, bucketed, y, b, out);
}

// Round 5
// 152.974 us; speedup vs baseline: 2.8440x; 1.0177x over previous
//
#include <hip/hip_runtime.h>

#define N_NODES 100000
#define D_FEAT 128
#define N_CLASSES 32
#define BSHIFT 8
#define NB 391            // ceil(100000/256) dst buckets of 256 nodes
#define EPB 4096          // edges per partition block
#define CAPB 5120         // per-bucket region capacity (mean 4092 + >8 sigma)
#define GCAP 1536         // per-quarter sorted capacity (mean 1023 + >8 sigma)

typedef __attribute__((ext_vector_type(8))) short short8;
typedef __attribute__((ext_vector_type(4))) float f32x4;

__device__ __forceinline__ unsigned short f2bf(float f) {
  unsigned u = __float_as_uint(f);
  u += 0x7fffu + ((u >> 16) & 1);   // round-to-nearest-even
  return (unsigned short)(u >> 16);
}

// pack two f32 -> two bf16 (RNE) in one instruction (T12 recipe)
__device__ __forceinline__ unsigned cvtpk(float lo, float hi) {
  unsigned r;
  asm("v_cvt_pk_bf16_f32 %0, %1, %2" : "=v"(r) : "v"(lo), "v"(hi));
  return r;
}

// ---------- prep: W -> bf16 + zero bucket counters ----------
__global__ __launch_bounds__(256) void gin_prep(const float* __restrict__ W,
                                                unsigned short* __restrict__ Wb,
                                                int* __restrict__ gcount) {
  int i = blockIdx.x * 256 + threadIdx.x;
  if (i < D_FEAT * N_CLASSES) Wb[i] = f2bf(W[i]);
  if (i < NB) gcount[i] = 0;
}

// ---------- fused mid: blocks [0,GBr) partition edges, rest MFMA projection ----------
// Partition (round-5 slim): edges read ONCE into registers -> LDS histogram ->
// reserve global per-bucket ranges (one atomicAdd per (block,bucket)) -> DIRECT
// scattered store to bucketed[b*CAPB + gbase[b]+r]. Runs of ~10 consecutive slots
// per (block,bucket) are written by a single block => ~2x line amp (round-3's 17x
// came from 16 different writer-blocks per line). No LDS sort, no scan, no binary
// search: LDS 22.4 KB -> 4.7 KB, so proj blocks are no longer LDS-capped.
__global__ __launch_bounds__(256) void gin_mid(
    const float* __restrict__ x, const unsigned short* __restrict__ Wb,
    float* __restrict__ y,
    const int* __restrict__ src, const int* __restrict__ dst,
    int* __restrict__ gcount, unsigned* __restrict__ bucketed,
    int E, int GBr) {
  __shared__ int cnt[NB];
  __shared__ int cur[NB];
  __shared__ int gbase[NB];
  int tid = threadIdx.x;

  if ((int)blockIdx.x >= GBr) {
    // ================= projection path =================
    int pb = blockIdx.x - GBr;
    int wave = tid >> 6, lane = tid & 63;
    int node_base = pb * 64 + wave * 16;
    if (node_base >= N_NODES) return;
    int m = lane & 15, quad = lane >> 4;

    short8 bfrag[2][4];
#pragma unroll
    for (int cb = 0; cb < 2; ++cb) {
      const unsigned short* wr = Wb + (cb * 16 + m) * D_FEAT + quad * 8;
#pragma unroll
      for (int ks = 0; ks < 4; ++ks)
        bfrag[cb][ks] = *(const short8*)(wr + ks * 32);
    }

    const float* xr = x + (size_t)(node_base + m) * D_FEAT + quad * 8;
    short8 afrag[4];
#pragma unroll
    for (int ks = 0; ks < 4; ++ks) {
      float4 f0 = *(const float4*)(xr + ks * 32);
      float4 f1 = *(const float4*)(xr + ks * 32 + 4);
      union { uint4 u; short8 s; } au;
      au.u.x = cvtpk(f0.x, f0.y);
      au.u.y = cvtpk(f0.z, f0.w);
      au.u.z = cvtpk(f1.x, f1.y);
      au.u.w = cvtpk(f1.z, f1.w);
      afrag[ks] = au.s;
    }

    f32x4 acc0 = {0.f, 0.f, 0.f, 0.f};
    f32x4 acc1 = {0.f, 0.f, 0.f, 0.f};
#pragma unroll
    for (int ks = 0; ks < 4; ++ks) {
      acc0 = __builtin_amdgcn_mfma_f32_16x16x32_bf16(afrag[ks], bfrag[0][ks], acc0, 0, 0, 0);
      acc1 = __builtin_amdgcn_mfma_f32_16x16x32_bf16(afrag[ks], bfrag[1][ks], acc1, 0, 0, 0);
    }

#pragma unroll
    for (int r = 0; r < 4; ++r) {
      int node = node_base + quad * 4 + r;
      y[(size_t)node * N_CLASSES + m] = acc0[r];
      y[(size_t)node * N_CLASSES + 16 + m] = acc1[r];
    }
    return;
  }

  // ================= partition path (4.7 KB LDS) =================
  int blk = blockIdx.x;
  for (int i = tid; i < NB; i += 256) {
    cnt[i] = 0;
    cur[i] = 0;
  }
  __syncthreads();
  int base = blk * EPB;
  bool full = (base + EPB <= E);

  // single global read of the edge list, held in registers
  int dv[16];
  unsigned sv[16];
  if (full) {
#pragma unroll
    for (int k = 0; k < 16; ++k) dv[k] = dst[base + k * 256 + tid];
#pragma unroll
    for (int k = 0; k < 16; ++k) sv[k] = (unsigned)src[base + k * 256 + tid];
  } else {
#pragma unroll
    for (int k = 0; k < 16; ++k) {
      int e = base + k * 256 + tid;
      dv[k] = (e < E) ? dst[e] : -1;
      sv[k] = (e < E) ? (unsigned)src[e] : 0u;
    }
  }
#pragma unroll
  for (int k = 0; k < 16; ++k)
    if (dv[k] >= 0) atomicAdd(&cnt[dv[k] >> BSHIFT], 1);
  __syncthreads();

  // reserve global ranges (within-bucket order is irrelevant -> no scan anywhere)
  for (int i = tid; i < NB; i += 256) {
    int c = cnt[i];
    gbase[i] = c ? atomicAdd(&gcount[i], c) : 0;
  }
  __syncthreads();

  // direct scattered store: run of cnt[b] consecutive slots per bucket
#pragma unroll
  for (int k = 0; k < 16; ++k) {
    if (dv[k] >= 0) {
      int b = dv[k] >> BSHIFT;
      int r = atomicAdd(&cur[b], 1);
      int ga = gbase[b] + r;
      if (ga < CAPB)
        bucketed[(size_t)b * CAPB + ga] = sv[k] | ((unsigned)(dv[k] & 255) << 17);
    }
  }
}

// ---------- gather: 4 blocks/bucket; ONE global pass (stage into LDS + count), ----------
// LDS->LDS counting-scatter, then 8-threads-per-node register accumulation.
__global__ __launch_bounds__(512) void gin_gather_s(
    const int* __restrict__ gcount, const unsigned* __restrict__ bucketed,
    const float* __restrict__ y, const float* __restrict__ bias,
    float* __restrict__ out) {
  __shared__ unsigned stage[CAPB];   // 20 KB
  __shared__ unsigned sorted[GCAP];  // 6 KB
  __shared__ int cnt[64];
  __shared__ int off[65];
  __shared__ int cur[64];
  int tid = threadIdx.x;
  int bk = blockIdx.x >> 2;
  int qq = blockIdx.x & 3;
  int len = gcount[bk];
  if (len > CAPB) len = CAPB;
  const unsigned* bb = bucketed + (size_t)bk * CAPB;
  if (tid < 64) cnt[tid] = 0;
  __syncthreads();
  // pass 1: global -> LDS stage, count own quarter
  for (int i = tid; i < len; i += 512) {
    unsigned p = bb[i];
    stage[i] = p;
    int n8 = (int)((p >> 17) & 255u);
    if ((n8 >> 6) == qq) atomicAdd(&cnt[n8 & 63], 1);
  }
  __syncthreads();
  if (tid == 0) off[0] = 0;
  if (tid < 64) off[tid + 1] = cnt[tid];
  __syncthreads();
  for (int o = 1; o < 64; o <<= 1) {
    int v = (tid < 64 && tid >= o) ? off[tid + 1 - o] : 0;
    __syncthreads();
    if (tid < 64) off[tid + 1] += v;
    __syncthreads();
  }
  if (tid < 64) cur[tid] = off[tid];
  __syncthreads();
  // pass 2: LDS -> LDS counting-scatter (no global re-read)
  for (int i = tid; i < len; i += 512) {
    unsigned p = stage[i];
    int n8 = (int)((p >> 17) & 255u);
    if ((n8 >> 6) == qq) {
      int pos = atomicAdd(&cur[n8 & 63], 1);
      if (pos < GCAP) sorted[pos] = p;
    }
  }
  __syncthreads();
  // accumulate: 8 threads per node, q = tid&7 owns one float4 column
  int nl = tid >> 3;                 // node-in-quarter 0..63
  int q = tid & 7;
  int es = off[nl], ee = off[nl + 1];
  if (ee > GCAP) ee = GCAP;
  if (es > ee) es = ee;
  int node = (bk << 8) + (qq << 6) + nl;
  if (node >= N_NODES) return;
  const float4* y4 = (const float4*)y;
  float4 bq = ((const float4*)bias)[q];
  float4 self = y4[(size_t)node * 8 + q];
  float4 acc;
  acc.x = self.x + bq.x;
  acc.y = self.y + bq.y;
  acc.z = self.z + bq.z;
  acc.w = self.w + bq.w;
  int j = es;
  for (; j + 4 <= ee; j += 4) {
    unsigned s0 = sorted[j] & 0x1FFFF, s1 = sorted[j + 1] & 0x1FFFF;
    unsigned s2 = sorted[j + 2] & 0x1FFFF, s3 = sorted[j + 3] & 0x1FFFF;
    float4 w0 = y4[(size_t)s0 * 8 + q];
    float4 w1 = y4[(size_t)s1 * 8 + q];
    float4 w2 = y4[(size_t)s2 * 8 + q];
    float4 w3 = y4[(size_t)s3 * 8 + q];
    acc.x += w0.x + w1.x + w2.x + w3.x;
    acc.y += w0.y + w1.y + w2.y + w3.y;
    acc.z += w0.z + w1.z + w2.z + w3.z;
    acc.w += w0.w + w1.w + w2.w + w3.w;
  }
  for (; j < ee; ++j) {
    float4 w = y4[(size_t)(sorted[j] & 0x1FFFF) * 8 + q];
    acc.x += w.x; acc.y += w.y; acc.z += w.z; acc.w += w.w;
  }
  ((float4*)out)[(size_t)node * 8 + q] = acc;
}

// ---------- fallback: bias init + atomic scatter ----------
__global__ __launch_bounds__(256) void gin_bias_init(
    const float* __restrict__ y, const float* __restrict__ b,
    float* __restrict__ out) {
  int gid = blockIdx.x * 256 + threadIdx.x;
  if (gid < N_NODES * N_CLASSES) out[gid] = y[gid] + b[gid & 31];
}
__global__ __launch_bounds__(256) void gin_scatter_fb(
    const int* __restrict__ src, const int* __restrict__ dst,
    const float* __restrict__ y, float* __restrict__ out, int n_edges) {
  long long gid = (long long)blockIdx.x * 256 + threadIdx.x;
  int e = (int)(gid >> 5);
  int c = (int)(gid & 31);
  if (e >= n_edges) return;
  atomicAdd(&out[(size_t)dst[e] * N_CLASSES + c],
            y[(size_t)src[e] * N_CLASSES + c]);
}

extern "C" void kernel_launch(void* const* d_in, const int* in_sizes, int n_in,
                              void* d_out, int out_size, void* d_ws, size_t ws_size,
                              hipStream_t stream) {
  const float* x = (const float*)d_in[0];
  const int* edge_index = (const int*)d_in[1];
  const float* W = (const float*)d_in[2];
  const float* b = (const float*)d_in[3];
  float* out = (float*)d_out;

  int E = in_sizes[1] / 2;
  const int* src = edge_index;
  const int* dst = edge_index + E;

  int GBr = (E + EPB - 1) / EPB;      // 391 for E=1.6M
  int pblocks = (N_NODES + 63) / 64;  // 1563 projection blocks (4 waves x 16 nodes)

  char* ws = (char*)d_ws;
  size_t sz_y = (size_t)N_NODES * N_CLASSES * 4;                 // 12.8 MB
  size_t sz_wb = (D_FEAT * N_CLASSES * 2 + 15) & ~15ull;         // 8 KB bf16 W
  size_t sz_bucketed = (((size_t)NB * CAPB * 4) + 15) & ~15ull;  // 8.0 MB
  size_t sz_gcnt = ((size_t)NB * 4 + 15) & ~15ull;

  float* y = (float*)ws;
  unsigned short* Wb = (unsigned short*)(ws + sz_y);
  unsigned* bucketed = (unsigned*)(ws + sz_y + sz_wb);
  int* gcount = (int*)(ws + sz_y + sz_wb + sz_bucketed);
  size_t need = sz_y + sz_wb + sz_bucketed + sz_gcnt;

  // capacity guard: CAPB=5120 covers mean E/391 + 8 sigma up to E ~ 1.75M
  bool dense = E > 1750000;

  if (ws_size < need || dense) {
    gin_prep<<<16, 256, 0, stream>>>(W, Wb, (int*)ws);  // scratch; y overwritten next
    gin_mid<<<pblocks, 256, 0, stream>>>(x, Wb, y, src, dst, (int*)ws, (unsigned*)ws, E, 0);
    gin_bias_init<<<(N_NODES * N_CLASSES + 255) / 256, 256, 0, stream>>>(y, b, out);
    long long t2 = (long long)E * N_CLASSES;
    gin_scatter_fb<<<(int)((t2 + 255) / 256), 256, 0, stream>>>(src, dst, y, out, E);
    return;
  }

  gin_prep<<<16, 256, 0, stream>>>(W, Wb, gcount);
  gin_mid<<<GBr + pblocks, 256, 0, stream>>>(x, Wb, y, src, dst, gcount, bucketed, E, GBr);
  gin_gather_s<<<NB * 4, 512, 0, stream>>>(gcount, bucketed, y, b, out);
}